// Round 10
// baseline (681.717 us; speedup 1.0000x reference)
//
#include <hip/hip_runtime.h>
#include <hip/hip_bf16.h>

// Problem constants (fixed by setup_inputs)
#define T_TOK 2048
#define DDIM  2048
#define IDIM  2816
#define NE    8
#define NPAIR (T_TOK*2)      // 4096 (token, k) pairs
#define GU_N  (2*IDIM)       // 5632

typedef __bf16  bf16x8 __attribute__((ext_vector_type(8)));
typedef float   f32x4  __attribute__((ext_vector_type(4)));
typedef int     int4v  __attribute__((ext_vector_type(4)));
typedef unsigned int uint2v __attribute__((ext_vector_type(2)));
typedef unsigned int uint4v __attribute__((ext_vector_type(4)));

// ws layout (bytes)
#define OFF_A   (64*1024)
#define OFF_GU  (OFF_A  + (size_t)NPAIR*DDIM*2)   // gu: 46.14 MB bf16 (linear)
#define OFF_H   (OFF_GU + (size_t)NPAIR*GU_N*2)   // h: 23 MB bf16 (pre-swizzled)
#define OFF_YP  (OFF_H  + (size_t)NPAIR*IDIM*2)   // yp: 32 MB f32
// Dense-weight overlays (R5/R6-proven, stream-serial lifetimes):
//   W13d (46.14 MB) at OFF_H  (h+yp dead during repack13/gemm1)
//   W2d  (23.07 MB) at OFF_GU (gu dead after act)
#define W13_DWORDS (NE*(size_t)GU_N*(DDIM/8))   // 11,534,336
#define W2_DWORDS  (NE*(size_t)DDIM*(IDIM/8))   //  5,767,168

__device__ __forceinline__ unsigned short f2bf(float f) {
    __hip_bfloat16 h = __float2bfloat16(f);
    return __builtin_bit_cast(unsigned short, h);
}
__device__ __forceinline__ float bf2f(unsigned short u) {
    unsigned int x = ((unsigned int)u) << 16;
    return __builtin_bit_cast(float, x);
}
__device__ __forceinline__ unsigned int pack2bf(float lo, float hi) {
    return ((unsigned int)f2bf(hi) << 16) | (unsigned int)f2bf(lo);
}
// async global->LDS, 16B per lane; LDS dest must be wave-uniform-base + lane*16
__device__ __forceinline__ void gload_lds16(const void* g, void* l) {
    __builtin_amdgcn_global_load_lds(
        (const __attribute__((address_space(1))) void*)g,
        (__attribute__((address_space(3))) void*)l, 16, 0, 0);
}

// ---------------- routing: stable compaction of 4096 pairs by expert ---------
// meta: [0..7]=cnt, [8..15]=off (exclusive prefix), [64..64+4095]=list (pair idx)
__global__ void route_kernel(const int* __restrict__ ids, int* __restrict__ meta) {
    __shared__ int histL[NE][256];
    __shared__ int totals[NE];
    __shared__ int offsS[NE];
    const int tid = threadIdx.x;
    for (int e = 0; e < NE; ++e) histL[e][tid] = 0;
    for (int j = 0; j < 16; ++j) {
        int id = ids[tid*16 + j];
        histL[id][tid]++;
    }
    __syncthreads();
    if (tid < NE) {
        int run = 0;
        for (int i = 0; i < 256; ++i) { int v = histL[tid][i]; histL[tid][i] = run; run += v; }
        totals[tid] = run;
    }
    __syncthreads();
    if (tid == 0) {
        int run = 0;
        for (int e = 0; e < NE; ++e) {
            offsS[e] = run;
            meta[e] = totals[e];
            meta[8+e] = run;
            run += totals[e];
        }
    }
    __syncthreads();
    for (int j = 0; j < 16; ++j) {
        int p = tid*16 + j;
        int id = ids[p];
        int local = histL[id][tid];
        histL[id][tid] = local + 1;
        meta[64 + offsS[id] + local] = p;
    }
}

// ---------------- gather: x rows -> compact PRE-SWIZZLED bf16 A matrix -------
// logical col-byte cb of row r stored at (cb&~127) | ((cb&127) ^ ((r&7)<<4))
__global__ void gather_kernel(const float* __restrict__ x, const int* __restrict__ meta,
                              unsigned short* __restrict__ Aall) {
    const int r = blockIdx.x;
    const int p = meta[64 + r];
    const int t = p >> 1;
    const int c = threadIdx.x * 8;
    const float4* src = (const float4*)(x + (size_t)t*DDIM + c);
    float4 f0 = src[0], f1 = src[1];
    unsigned short o[8];
    o[0]=f2bf(f0.x); o[1]=f2bf(f0.y); o[2]=f2bf(f0.z); o[3]=f2bf(f0.w);
    o[4]=f2bf(f1.x); o[5]=f2bf(f1.y); o[6]=f2bf(f1.z); o[7]=f2bf(f1.w);
    int cb  = c * 2;
    int cbs = (cb & ~127) | ((cb & 127) ^ ((r & 7) << 4));
    *(uint4v*)((char*)Aall + (size_t)r*(DDIM*2) + cbs) = *(uint4v*)o;
}

// ---------------- repackB: sparse int4 -> FRAGMENT-MAJOR dense words ---------
// Dense word (row, kt, kk, lk) covers weights k = kt*64+kk*32+lk*8 .. +7
// (byte b = low byte of src int 4w+b, exactly the R6 packing -> same values).
// Stored at tile-major offset: tile = (e*(N/16) + row/16)*KT64 + kt (512B tile),
// within-tile word = (row&15)*8 + lk*2 + kk. A GEMM wave's uint2v load at
// lr*8 + lk*2 then covers each tile exactly (coalesced 512B per wave).
__global__ void repackB_kernel(const int* __restrict__ src,
                               unsigned int* __restrict__ dst,
                               int N16, int KT64, int rowints, int nwords4) {
    const int i4 = blockIdx.x * 256 + threadIdx.x;
    if (i4 >= nwords4) return;
    const int d0   = i4 * 4;
    const int tile = d0 >> 7;
    const int iw   = d0 & 127;
    const int rowg = iw >> 3;             // row within 16-group
    const int half = (iw >> 2) & 1;       // which 4 of the 8 per-row words
    const int kt   = tile % KT64;
    const int rge  = tile / KT64;
    const int rg   = rge % N16;
    const int e    = rge / N16;
    const int row  = rg*16 + rowg;
    const int* srow = src + ((size_t)e*(N16*16) + row) * rowints;
    uint4v o;
#pragma unroll
    for (int q = 0; q < 4; ++q) {
        int rr = half*4 + q;
        int lk = rr >> 1, kk = rr & 1;
        int w  = kt*8 + kk*4 + lk;        // natural k-order dense word index
        int4v p = *(const int4v*)(srow + (size_t)w*4);
        o[q] = ((unsigned int)p[0] & 0xFFu)
             | (((unsigned int)p[1] & 0xFFu) << 8)
             | (((unsigned int)p[2] & 0xFFu) << 16)
             | (((unsigned int)p[3] & 0xFFu) << 24);
    }
    *(uint4v*)(dst + (size_t)d0) = o;
}

// ============ single-barrier reg-B dequant-GEMM macros =======================
// ISSUE_A: async-copy A K-slab KT into As[SEL] (linear copy of pre-swizzled rows)
#define ISSUE_A(SEL, KT) do {                                              \
    _Pragma("unroll")                                                      \
    for (int _i = 0; _i < 4; ++_i)                                         \
        gload_lds16(a_src[_i] + (size_t)(KT)*128,                          \
                    (char*)&As[SEL][0] + wv*4096 + _i*1024 + lane*16);     \
} while (0)

// LOADB: 4 x dwordx2 of this lane's B-fragment words for K-tile KT
#define LOADB(PK, KT) do {                                                 \
    _Pragma("unroll")                                                      \
    for (int _nj = 0; _nj < 4; ++_nj)                                      \
        PK[_nj] = *(const uint2v*)(Bp + bwo0 + _nj*NJSTEP + (size_t)(KT)*128); \
} while (0)

// LOADS: per-nj scale/zp for group G (prefetched one pair ahead)
#define LOADS(S, C, G) do {                                                \
    _Pragma("unroll")                                                      \
    for (int _nj = 0; _nj < 4; ++_nj) {                                    \
        float _s = wsc[swo0 + _nj*SSTEP + (G)];                            \
        float _z = wzp[swo0 + _nj*SSTEP + (G)];                            \
        S[_nj] = _s; C[_nj] = -_z*_s;                                      \
    }                                                                      \
} while (0)

// DEQ_FRAG: one dense word -> bf16x8 fragment (bit-identical math to R6)
#define DEQ_FRAG(BF, W, S, C) do {                                        \
    unsigned int _loq = (W) & 0x0F0F0F0Fu;                                 \
    unsigned int _hiq = ((W) >> 4) & 0x0F0F0F0Fu;                          \
    uint4v _o;                                                             \
    _Pragma("unroll")                                                      \
    for (int _j = 0; _j < 4; ++_j) {                                       \
        float _flo = (float)((_loq >> (8*_j)) & 0xFFu);                    \
        float _fhi = (float)((_hiq >> (8*_j)) & 0xFFu);                    \
        _o[_j] = pack2bf(fmaf(_flo, (S), (C)), fmaf(_fhi, (S), (C)));      \
    }                                                                      \
    BF = __builtin_bit_cast(bf16x8, _o);                                   \
} while (0)

// MFMA_STEP: A frags from LDS (base7 XOR), B frags dequanted in-register
#define MFMA_STEP(SEL, PK, S, C) do {                                      \
    _Pragma("unroll")                                                      \
    for (int _kk = 0; _kk < 2; ++_kk) {                                    \
        bf16x8 _af[4];                                                     \
        const int _kbyte = _kk*64 + lk*16;                                 \
        _Pragma("unroll")                                                  \
        for (int _mi = 0; _mi < 4; ++_mi) {                                \
            int _row = wm + _mi*16 + lr;                                   \
            int _b = _kbyte ^ (((_row + base7) & 7) << 4);                 \
            _af[_mi] = *(const bf16x8*)(&As[SEL][_row*64 + (_b >> 1)]);    \
        }                                                                  \
        _Pragma("unroll")                                                  \
        for (int _nj = 0; _nj < 4; ++_nj) {                                \
            bf16x8 _bf;                                                    \
            DEQ_FRAG(_bf, PK[_nj][_kk], S[_nj], C[_nj]);                   \
            _Pragma("unroll")                                              \
            for (int _mi = 0; _mi < 4; ++_mi)                              \
                acc[_mi][_nj] = __builtin_amdgcn_mfma_f32_16x16x32_bf16(   \
                    _af[_mi], _bf, acc[_mi][_nj], 0, 0, 0);                \
        }                                                                  \
    }                                                                      \
} while (0)

// K-pair: ONE barrier per step. Each barrier's implicit vmcnt(0) drains loads
// issued AFTER the previous barrier — aged by a full DEQ+MFMA phase (~700cy)
// -> ~zero exposure. No Bs, no ds_write, no barrier2 (each wave dequants its
// own B fragments; the 2x DEQ redundancy buys the barrier away). 32KB LDS +
// <=128 VGPR -> 4 blocks/CU (16 waves, vs R6's 12).
#define STEP_PAIR(KT) do {                                                 \
    __syncthreads();                                                       \
    ISSUE_A(1, (KT)+1);                                                    \
    LOADB(pY, (KT)+1);                                                     \
    int _gn = ((KT)>>1) + 1; if (_gn > NG-1) _gn = NG-1;                   \
    LOADS(sN, cN, _gn);                                                    \
    MFMA_STEP(0, pX, sC, cC);                                              \
    __syncthreads();                                                       \
    int _ktn = (KT)+2 < NT ? (KT)+2 : NT-1;                                \
    ISSUE_A(0, _ktn);                                                      \
    LOADB(pX, _ktn);                                                       \
    MFMA_STEP(1, pY, sC, cC);                                              \
    _Pragma("unroll")                                                      \
    for (int _j = 0; _j < 4; ++_j) { sC[_j] = sN[_j]; cC[_j] = cN[_j]; }   \
} while (0)

// ---------------- GEMM1: A[4096,2048]bf16 x W13d[e]^T (frag-major int4) ------
__launch_bounds__(256, 4)
__global__ void gemm1_kernel(const unsigned short* __restrict__ Aall,
                             const unsigned int* __restrict__ Bp,
                             const float* __restrict__ wsc,
                             const float* __restrict__ wzp,
                             const int* __restrict__ meta,
                             unsigned short* __restrict__ gu) {
    const int e   = blockIdx.z;
    const int cnt = meta[e];
    const int m0  = blockIdx.y * 128;
    if (m0 >= cnt) return;
    const int off = meta[8 + e];
    const int n0  = blockIdx.x * 128;
    const int tid = threadIdx.x;

    __shared__ unsigned short As[2][128*64];   // 32 KB total

    f32x4 acc[4][4];
#pragma unroll
    for (int i = 0; i < 4; ++i)
#pragma unroll
        for (int j = 0; j < 4; ++j) acc[i][j] = (f32x4)0.0f;

    const int lane = tid & 63;
    const int wv   = tid >> 6;
    const char* a_src[4];
#pragma unroll
    for (int i = 0; i < 4; ++i) {
        int lrow  = wv*32 + i*8 + (lane >> 3);
        int garow = off + m0 + lrow; if (garow > NPAIR-1) garow = NPAIR-1;
        a_src[i] = (const char*)Aall + (size_t)garow*(DDIM*2) + (lane & 7)*16;
    }
    const int base7 = (off + m0) & 7;

    const int wm = (wv >> 1) * 64, wn = (wv & 1) * 64;
    const int lr = lane & 15, lk = lane >> 4;

    const int NT = DDIM/64;    // 32
    const int NG = DDIM/128;   // 16
    const int NJSTEP = 32*128; // KT64 tiles * 128 words per 16-row group
    const int SSTEP  = 16*(DDIM/128);
    const size_t bwo0 = ((size_t)(e*(GU_N/16) + ((n0 + wn) >> 4)))*(size_t)NJSTEP
                      + (size_t)(lr*8 + lk*2);
    const size_t swo0 = ((size_t)e*GU_N + (n0 + wn + lr))*(DDIM/128);

    uint2v pX[4], pY[4];
    float sC[4], cC[4], sN[4], cN[4];

    ISSUE_A(0, 0);
    LOADB(pX, 0);
    LOADS(sC, cC, 0);
    for (int kt = 0; kt < NT; kt += 2) STEP_PAIR(kt);
    __syncthreads();   // drain trailing prefetch DMA before LDS dealloc

    // epilogue: C[m][n] lane map col=lane&15, row=(lane>>4)*4+reg (m89)
#pragma unroll
    for (int mi = 0; mi < 4; ++mi)
#pragma unroll
        for (int nj = 0; nj < 4; ++nj) {
            f32x4 v = acc[mi][nj];
            int col = n0 + wn + nj*16 + lr;
#pragma unroll
            for (int r = 0; r < 4; ++r) {
                int row = wm + mi*16 + lk*4 + r;
                if (m0 + row < cnt)
                    gu[(size_t)(off + m0 + row)*GU_N + col] = f2bf(v[r]);
            }
        }
}

// ---------------- activation: h = silu(g)*u, written PRE-SWIZZLED ------------
__global__ void act_kernel(const unsigned short* __restrict__ gu,
                           unsigned short* __restrict__ h) {
    const int r = blockIdx.x;
    for (int c = threadIdx.x; c < IDIM/8; c += 256) {
        uint4v g8 = *(const uint4v*)(&gu[(size_t)r*GU_N + c*8]);
        uint4v u8 = *(const uint4v*)(&gu[(size_t)r*GU_N + IDIM + c*8]);
        const unsigned short* gp = (const unsigned short*)&g8;
        const unsigned short* up = (const unsigned short*)&u8;
        unsigned short o[8];
#pragma unroll
        for (int j = 0; j < 8; ++j) {
            float g = bf2f(gp[j]), u = bf2f(up[j]);
            float sg = g / (1.0f + __expf(-g));
            o[j] = f2bf(sg * u);
        }
        int cb  = c * 16;
        int cbs = (cb & ~127) | ((cb & 127) ^ ((r & 7) << 4));
        *(uint4v*)((char*)h + (size_t)r*(IDIM*2) + cbs) = *(uint4v*)o;
    }
}

// ---------------- GEMM2: h[4096,2816]bf16 x W2d[e]^T (frag-major int4) -------
__launch_bounds__(256, 4)
__global__ void gemm2_kernel(const unsigned short* __restrict__ h,
                             const unsigned int* __restrict__ Bp,
                             const float* __restrict__ wsc,
                             const float* __restrict__ wzp,
                             const float* __restrict__ tw,
                             const int* __restrict__ meta,
                             float* __restrict__ yp) {
    const int e   = blockIdx.z;
    const int cnt = meta[e];
    const int m0  = blockIdx.y * 128;
    if (m0 >= cnt) return;
    const int off = meta[8 + e];
    const int n0  = blockIdx.x * 128;
    const int tid = threadIdx.x;

    __shared__ unsigned short As[2][128*64];   // 32 KB total

    f32x4 acc[4][4];
#pragma unroll
    for (int i = 0; i < 4; ++i)
#pragma unroll
        for (int j = 0; j < 4; ++j) acc[i][j] = (f32x4)0.0f;

    const int lane = tid & 63;
    const int wv   = tid >> 6;
    const char* a_src[4];
#pragma unroll
    for (int i = 0; i < 4; ++i) {
        int lrow  = wv*32 + i*8 + (lane >> 3);
        int garow = off + m0 + lrow; if (garow > NPAIR-1) garow = NPAIR-1;
        a_src[i] = (const char*)h + (size_t)garow*(IDIM*2) + (lane & 7)*16;
    }
    const int base7 = (off + m0) & 7;

    const int wm = (wv >> 1) * 64, wn = (wv & 1) * 64;
    const int lr = lane & 15, lk = lane >> 4;

    const int NT = IDIM/64;    // 44
    const int NG = IDIM/128;   // 22
    const int NJSTEP = 44*128;
    const int SSTEP  = 16*(IDIM/128);
    const size_t bwo0 = ((size_t)(e*(DDIM/16) + ((n0 + wn) >> 4)))*(size_t)NJSTEP
                      + (size_t)(lr*8 + lk*2);
    const size_t swo0 = ((size_t)e*DDIM + (n0 + wn + lr))*(IDIM/128);

    uint2v pX[4], pY[4];
    float sC[4], cC[4], sN[4], cN[4];

    ISSUE_A(0, 0);
    LOADB(pX, 0);
    LOADS(sC, cC, 0);
    for (int kt = 0; kt < NT; kt += 2) STEP_PAIR(kt);
    __syncthreads();   // drain trailing prefetch DMA before LDS dealloc

#pragma unroll
    for (int mi = 0; mi < 4; ++mi)
#pragma unroll
        for (int nj = 0; nj < 4; ++nj) {
            f32x4 v = acc[mi][nj];
            int col = n0 + wn + nj*16 + lr;
#pragma unroll
            for (int r = 0; r < 4; ++r) {
                int row = wm + mi*16 + lk*4 + r;
                if (m0 + row < cnt) {
                    int p = meta[64 + off + m0 + row];
                    float w = tw[p];
                    yp[(size_t)p*DDIM + col] = v[r] * w;
                }
            }
        }
}

// ---------------- combine: out[t] = yp[2t] + yp[2t+1] ------------------------
__global__ void combine_kernel(const float* __restrict__ yp, float* __restrict__ out) {
    const int i = blockIdx.x * 256 + threadIdx.x;      // float4 index
    const int t = i >> 9, d = i & 511;
    const f32x4* a = (const f32x4*)yp;
    f32x4 va = a[(size_t)(t*2)*512 + d];
    f32x4 vb = a[(size_t)(t*2+1)*512 + d];
    ((f32x4*)out)[i] = va + vb;
}

extern "C" void kernel_launch(void* const* d_in, const int* in_sizes, int n_in,
                              void* d_out, int out_size, void* d_ws, size_t ws_size,
                              hipStream_t stream) {
    const float* x    = (const float*)d_in[0];
    const int*   ids  = (const int*)d_in[1];
    const float* tw   = (const float*)d_in[2];
    const int*   w13p = (const int*)d_in[3];
    const float* w13s = (const float*)d_in[4];
    const float* w13z = (const float*)d_in[5];
    const int*   w2p  = (const int*)d_in[6];
    const float* w2s  = (const float*)d_in[7];
    const float* w2z  = (const float*)d_in[8];
    float* out = (float*)d_out;

    char* ws = (char*)d_ws;
    int* meta = (int*)ws;
    unsigned short* Aall = (unsigned short*)(ws + OFF_A);
    unsigned short* gu   = (unsigned short*)(ws + OFF_GU);
    unsigned short* h    = (unsigned short*)(ws + OFF_H);
    float* yp            = (float*)(ws + OFF_YP);
    // dense-weight overlays (lifetimes disjoint with the regions they borrow)
    unsigned int* W13d = (unsigned int*)(ws + OFF_H);
    unsigned int* W2d  = (unsigned int*)(ws + OFF_GU);

    route_kernel<<<1, 256, 0, stream>>>(ids, meta);
    gather_kernel<<<NPAIR, 256, 0, stream>>>(x, meta, Aall);
    repackB_kernel<<<(int)(W13_DWORDS/1024), 256, 0, stream>>>(
        w13p, W13d, GU_N/16, DDIM/64, DDIM/2, (int)(W13_DWORDS/4));
    gemm1_kernel<<<dim3(GU_N/128, NPAIR/128, NE), 256, 0, stream>>>(
        Aall, W13d, w13s, w13z, meta, gu);
    act_kernel<<<NPAIR, 256, 0, stream>>>(gu, h);
    repackB_kernel<<<(int)(W2_DWORDS/1024), 256, 0, stream>>>(
        w2p, W2d, DDIM/16, IDIM/64, IDIM/2, (int)(W2_DWORDS/4));
    gemm2_kernel<<<dim3(DDIM/128, NPAIR/128, NE), 256, 0, stream>>>(
        h, W2d, w2s, w2z, tw, meta, yp);
    combine_kernel<<<(T_TOK*DDIM/4)/256, 256, 0, stream>>>(yp, out);
}

// Round 11
// 470.134 us; speedup vs baseline: 1.4501x; 1.4501x over previous
//
#include <hip/hip_runtime.h>
#include <hip/hip_bf16.h>

// Problem constants (fixed by setup_inputs)
#define T_TOK 2048
#define DDIM  2048
#define IDIM  2816
#define NE    8
#define NPAIR (T_TOK*2)      // 4096 (token, k) pairs
#define GU_N  (2*IDIM)       // 5632

typedef __bf16  bf16x8 __attribute__((ext_vector_type(8)));
typedef float   f32x4  __attribute__((ext_vector_type(4)));
typedef int     int4v  __attribute__((ext_vector_type(4)));
typedef unsigned int uint2v __attribute__((ext_vector_type(2)));
typedef unsigned int uint4v __attribute__((ext_vector_type(4)));

// ws layout (bytes)
#define OFF_A   (64*1024)
#define OFF_GU  (OFF_A  + (size_t)NPAIR*DDIM*2)   // gu: 46.14 MB bf16 (linear)
#define OFF_H   (OFF_GU + (size_t)NPAIR*GU_N*2)   // h: 23 MB bf16 (pre-swizzled)
#define OFF_YP  (OFF_H  + (size_t)NPAIR*IDIM*2)   // yp: 32 MB f32
// Dense-weight overlays (R5/R6-proven, stream-serial lifetimes):
//   W13d (46.14 MB) at OFF_H  (h+yp dead during repack13/gemm1)
//   W2d  (23.07 MB) at OFF_GU (gu dead after act)
#define W13_DWORDS (NE*(size_t)GU_N*(DDIM/8))   // 11,534,336
#define W2_DWORDS  (NE*(size_t)DDIM*(IDIM/8))   //  5,767,168

__device__ __forceinline__ unsigned short f2bf(float f) {
    __hip_bfloat16 h = __float2bfloat16(f);
    return __builtin_bit_cast(unsigned short, h);
}
__device__ __forceinline__ float bf2f(unsigned short u) {
    unsigned int x = ((unsigned int)u) << 16;
    return __builtin_bit_cast(float, x);
}
__device__ __forceinline__ unsigned int pack2bf(float lo, float hi) {
    return ((unsigned int)f2bf(hi) << 16) | (unsigned int)f2bf(lo);
}
// async global->LDS, 16B per lane; LDS dest must be wave-uniform-base + lane*16
__device__ __forceinline__ void gload_lds16(const void* g, void* l) {
    __builtin_amdgcn_global_load_lds(
        (const __attribute__((address_space(1))) void*)g,
        (__attribute__((address_space(3))) void*)l, 16, 0, 0);
}

// ---------------- routing: stable compaction of 4096 pairs by expert ---------
// meta: [0..7]=cnt, [8..15]=off (exclusive prefix), [64..64+4095]=list (pair idx)
__global__ void route_kernel(const int* __restrict__ ids, int* __restrict__ meta) {
    __shared__ int histL[NE][256];
    __shared__ int totals[NE];
    __shared__ int offsS[NE];
    const int tid = threadIdx.x;
    for (int e = 0; e < NE; ++e) histL[e][tid] = 0;
    for (int j = 0; j < 16; ++j) {
        int id = ids[tid*16 + j];
        histL[id][tid]++;
    }
    __syncthreads();
    if (tid < NE) {
        int run = 0;
        for (int i = 0; i < 256; ++i) { int v = histL[tid][i]; histL[tid][i] = run; run += v; }
        totals[tid] = run;
    }
    __syncthreads();
    if (tid == 0) {
        int run = 0;
        for (int e = 0; e < NE; ++e) {
            offsS[e] = run;
            meta[e] = totals[e];
            meta[8+e] = run;
            run += totals[e];
        }
    }
    __syncthreads();
    for (int j = 0; j < 16; ++j) {
        int p = tid*16 + j;
        int id = ids[p];
        int local = histL[id][tid];
        histL[id][tid] = local + 1;
        meta[64 + offsS[id] + local] = p;
    }
}

// ---------------- gather: x rows -> compact PRE-SWIZZLED bf16 A matrix -------
// logical col-byte cb of row r stored at (cb&~127) | ((cb&127) ^ ((r&7)<<4))
__global__ void gather_kernel(const float* __restrict__ x, const int* __restrict__ meta,
                              unsigned short* __restrict__ Aall) {
    const int r = blockIdx.x;
    const int p = meta[64 + r];
    const int t = p >> 1;
    const int c = threadIdx.x * 8;
    const float4* src = (const float4*)(x + (size_t)t*DDIM + c);
    float4 f0 = src[0], f1 = src[1];
    unsigned short o[8];
    o[0]=f2bf(f0.x); o[1]=f2bf(f0.y); o[2]=f2bf(f0.z); o[3]=f2bf(f0.w);
    o[4]=f2bf(f1.x); o[5]=f2bf(f1.y); o[6]=f2bf(f1.z); o[7]=f2bf(f1.w);
    int cb  = c * 2;
    int cbs = (cb & ~127) | ((cb & 127) ^ ((r & 7) << 4));
    *(uint4v*)((char*)Aall + (size_t)r*(DDIM*2) + cbs) = *(uint4v*)o;
}

// ---------------- repackB: sparse int4 -> FRAGMENT-MAJOR dense words ---------
// Dense word (row, kt, kk, lk) covers weights k = kt*64+kk*32+lk*8 .. +7
// (byte b = low byte of src int 4w+b, exactly the R6 packing -> same values).
// Stored at tile-major offset: tile = (e*(N/16) + row/16)*KT64 + kt (512B tile),
// within-tile word = (row&15)*8 + lk*2 + kk. A GEMM wave's uint2v load at
// lr*8 + lk*2 then covers each tile exactly (coalesced 512B per wave).
__global__ void repackB_kernel(const int* __restrict__ src,
                               unsigned int* __restrict__ dst,
                               int N16, int KT64, int rowints, int nwords4) {
    const int i4 = blockIdx.x * 256 + threadIdx.x;
    if (i4 >= nwords4) return;
    const int d0   = i4 * 4;
    const int tile = d0 >> 7;
    const int iw   = d0 & 127;
    const int rowg = iw >> 3;             // row within 16-group
    const int half = (iw >> 2) & 1;       // which 4 of the 8 per-row words
    const int kt   = tile % KT64;
    const int rge  = tile / KT64;
    const int rg   = rge % N16;
    const int e    = rge / N16;
    const int row  = rg*16 + rowg;
    const int* srow = src + ((size_t)e*(N16*16) + row) * rowints;
    uint4v o;
#pragma unroll
    for (int q = 0; q < 4; ++q) {
        int rr = half*4 + q;
        int lk = rr >> 1, kk = rr & 1;
        int w  = kt*8 + kk*4 + lk;        // natural k-order dense word index
        int4v p = *(const int4v*)(srow + (size_t)w*4);
        o[q] = ((unsigned int)p[0] & 0xFFu)
             | (((unsigned int)p[1] & 0xFFu) << 8)
             | (((unsigned int)p[2] & 0xFFu) << 16)
             | (((unsigned int)p[3] & 0xFFu) << 24);
    }
    *(uint4v*)(dst + (size_t)d0) = o;
}

// ============ single-barrier reg-B dequant-GEMM macros =======================
// ISSUE_A: async-copy A K-slab KT into As[SEL] (linear copy of pre-swizzled rows)
#define ISSUE_A(SEL, KT) do {                                              \
    _Pragma("unroll")                                                      \
    for (int _i = 0; _i < 4; ++_i)                                         \
        gload_lds16(a_src[_i] + (size_t)(KT)*128,                          \
                    (char*)&As[SEL][0] + wv*4096 + _i*1024 + lane*16);     \
} while (0)

// LOADB: 4 x dwordx2 of this lane's B-fragment words for K-tile KT
#define LOADB(PK, KT) do {                                                 \
    _Pragma("unroll")                                                      \
    for (int _nj = 0; _nj < 4; ++_nj)                                      \
        PK[_nj] = *(const uint2v*)(Bp + bwo0 + _nj*NJSTEP + (size_t)(KT)*128); \
} while (0)

// LOADS: per-nj scale/zp for group G (prefetched one pair ahead)
#define LOADS(S, C, G) do {                                                \
    _Pragma("unroll")                                                      \
    for (int _nj = 0; _nj < 4; ++_nj) {                                    \
        float _s = wsc[swo0 + _nj*SSTEP + (G)];                            \
        float _z = wzp[swo0 + _nj*SSTEP + (G)];                            \
        S[_nj] = _s; C[_nj] = -_z*_s;                                      \
    }                                                                      \
} while (0)

// DEQ_FRAG: one dense word -> bf16x8 fragment (bit-identical math to R6)
#define DEQ_FRAG(BF, W, S, C) do {                                        \
    unsigned int _loq = (W) & 0x0F0F0F0Fu;                                 \
    unsigned int _hiq = ((W) >> 4) & 0x0F0F0F0Fu;                          \
    uint4v _o;                                                             \
    _Pragma("unroll")                                                      \
    for (int _j = 0; _j < 4; ++_j) {                                       \
        float _flo = (float)((_loq >> (8*_j)) & 0xFFu);                    \
        float _fhi = (float)((_hiq >> (8*_j)) & 0xFFu);                    \
        _o[_j] = pack2bf(fmaf(_flo, (S), (C)), fmaf(_fhi, (S), (C)));      \
    }                                                                      \
    BF = __builtin_bit_cast(bf16x8, _o);                                   \
} while (0)

// MFMA_STEP: A frags from LDS (base7 XOR), B frags dequanted in-register
#define MFMA_STEP(SEL, PK, S, C) do {                                      \
    _Pragma("unroll")                                                      \
    for (int _kk = 0; _kk < 2; ++_kk) {                                    \
        bf16x8 _af[4];                                                     \
        const int _kbyte = _kk*64 + lk*16;                                 \
        _Pragma("unroll")                                                  \
        for (int _mi = 0; _mi < 4; ++_mi) {                                \
            int _row = wm + _mi*16 + lr;                                   \
            int _b = _kbyte ^ (((_row + base7) & 7) << 4);                 \
            _af[_mi] = *(const bf16x8*)(&As[SEL][_row*64 + (_b >> 1)]);    \
        }                                                                  \
        _Pragma("unroll")                                                  \
        for (int _nj = 0; _nj < 4; ++_nj) {                                \
            bf16x8 _bf;                                                    \
            DEQ_FRAG(_bf, PK[_nj][_kk], S[_nj], C[_nj]);                   \
            _Pragma("unroll")                                              \
            for (int _mi = 0; _mi < 4; ++_mi)                              \
                acc[_mi][_nj] = __builtin_amdgcn_mfma_f32_16x16x32_bf16(   \
                    _af[_mi], _bf, acc[_mi][_nj], 0, 0, 0);                \
        }                                                                  \
    }                                                                      \
} while (0)

// K-pair: ONE barrier per step. Each barrier's implicit vmcnt(0) drains loads
// issued AFTER the previous barrier — aged by a full DEQ+MFMA phase (~700cy)
// -> ~zero exposure. No Bs, no ds_write, no barrier2 (each wave dequants its
// own B fragments; the 2x DEQ redundancy buys the barrier away).
// R10 ran this at __launch_bounds__(256,4): the 128-reg cap spilled the
// accumulator (VGPR=64 reported, +395MB scratch WRITE). R11 = same structure
// at (256,3): cap 170 >> ~130 live regs -> no spill, 3 blocks/CU = 12 waves.
#define STEP_PAIR(KT) do {                                                 \
    __syncthreads();                                                       \
    ISSUE_A(1, (KT)+1);                                                    \
    LOADB(pY, (KT)+1);                                                     \
    int _gn = ((KT)>>1) + 1; if (_gn > NG-1) _gn = NG-1;                   \
    LOADS(sN, cN, _gn);                                                    \
    MFMA_STEP(0, pX, sC, cC);                                              \
    __syncthreads();                                                       \
    int _ktn = (KT)+2 < NT ? (KT)+2 : NT-1;                                \
    ISSUE_A(0, _ktn);                                                      \
    LOADB(pX, _ktn);                                                       \
    MFMA_STEP(1, pY, sC, cC);                                              \
    _Pragma("unroll")                                                      \
    for (int _j = 0; _j < 4; ++_j) { sC[_j] = sN[_j]; cC[_j] = cN[_j]; }   \
} while (0)

// ---------------- GEMM1: A[4096,2048]bf16 x W13d[e]^T (frag-major int4) ------
__launch_bounds__(256, 3)
__global__ void gemm1_kernel(const unsigned short* __restrict__ Aall,
                             const unsigned int* __restrict__ Bp,
                             const float* __restrict__ wsc,
                             const float* __restrict__ wzp,
                             const int* __restrict__ meta,
                             unsigned short* __restrict__ gu) {
    const int e   = blockIdx.z;
    const int cnt = meta[e];
    const int m0  = blockIdx.y * 128;
    if (m0 >= cnt) return;
    const int off = meta[8 + e];
    const int n0  = blockIdx.x * 128;
    const int tid = threadIdx.x;

    __shared__ unsigned short As[2][128*64];   // 32 KB total

    f32x4 acc[4][4];
#pragma unroll
    for (int i = 0; i < 4; ++i)
#pragma unroll
        for (int j = 0; j < 4; ++j) acc[i][j] = (f32x4)0.0f;

    const int lane = tid & 63;
    const int wv   = tid >> 6;
    const char* a_src[4];
#pragma unroll
    for (int i = 0; i < 4; ++i) {
        int lrow  = wv*32 + i*8 + (lane >> 3);
        int garow = off + m0 + lrow; if (garow > NPAIR-1) garow = NPAIR-1;
        a_src[i] = (const char*)Aall + (size_t)garow*(DDIM*2) + (lane & 7)*16;
    }
    const int base7 = (off + m0) & 7;

    const int wm = (wv >> 1) * 64, wn = (wv & 1) * 64;
    const int lr = lane & 15, lk = lane >> 4;

    const int NT = DDIM/64;    // 32
    const int NG = DDIM/128;   // 16
    const int NJSTEP = 32*128; // KT64 tiles * 128 words per 16-row group
    const int SSTEP  = 16*(DDIM/128);
    const size_t bwo0 = ((size_t)(e*(GU_N/16) + ((n0 + wn) >> 4)))*(size_t)NJSTEP
                      + (size_t)(lr*8 + lk*2);
    const size_t swo0 = ((size_t)e*GU_N + (n0 + wn + lr))*(DDIM/128);

    uint2v pX[4], pY[4];
    float sC[4], cC[4], sN[4], cN[4];

    ISSUE_A(0, 0);
    LOADB(pX, 0);
    LOADS(sC, cC, 0);
    for (int kt = 0; kt < NT; kt += 2) STEP_PAIR(kt);
    __syncthreads();   // drain trailing prefetch DMA before LDS dealloc

    // epilogue: C[m][n] lane map col=lane&15, row=(lane>>4)*4+reg (m89)
#pragma unroll
    for (int mi = 0; mi < 4; ++mi)
#pragma unroll
        for (int nj = 0; nj < 4; ++nj) {
            f32x4 v = acc[mi][nj];
            int col = n0 + wn + nj*16 + lr;
#pragma unroll
            for (int r = 0; r < 4; ++r) {
                int row = wm + mi*16 + lk*4 + r;
                if (m0 + row < cnt)
                    gu[(size_t)(off + m0 + row)*GU_N + col] = f2bf(v[r]);
            }
        }
}

// ---------------- activation: h = silu(g)*u, written PRE-SWIZZLED ------------
__global__ void act_kernel(const unsigned short* __restrict__ gu,
                           unsigned short* __restrict__ h) {
    const int r = blockIdx.x;
    for (int c = threadIdx.x; c < IDIM/8; c += 256) {
        uint4v g8 = *(const uint4v*)(&gu[(size_t)r*GU_N + c*8]);
        uint4v u8 = *(const uint4v*)(&gu[(size_t)r*GU_N + IDIM + c*8]);
        const unsigned short* gp = (const unsigned short*)&g8;
        const unsigned short* up = (const unsigned short*)&u8;
        unsigned short o[8];
#pragma unroll
        for (int j = 0; j < 8; ++j) {
            float g = bf2f(gp[j]), u = bf2f(up[j]);
            float sg = g / (1.0f + __expf(-g));
            o[j] = f2bf(sg * u);
        }
        int cb  = c * 16;
        int cbs = (cb & ~127) | ((cb & 127) ^ ((r & 7) << 4));
        *(uint4v*)((char*)h + (size_t)r*(IDIM*2) + cbs) = *(uint4v*)o;
    }
}

// ---------------- GEMM2: h[4096,2816]bf16 x W2d[e]^T (frag-major int4) -------
__launch_bounds__(256, 3)
__global__ void gemm2_kernel(const unsigned short* __restrict__ h,
                             const unsigned int* __restrict__ Bp,
                             const float* __restrict__ wsc,
                             const float* __restrict__ wzp,
                             const float* __restrict__ tw,
                             const int* __restrict__ meta,
                             float* __restrict__ yp) {
    const int e   = blockIdx.z;
    const int cnt = meta[e];
    const int m0  = blockIdx.y * 128;
    if (m0 >= cnt) return;
    const int off = meta[8 + e];
    const int n0  = blockIdx.x * 128;
    const int tid = threadIdx.x;

    __shared__ unsigned short As[2][128*64];   // 32 KB total

    f32x4 acc[4][4];
#pragma unroll
    for (int i = 0; i < 4; ++i)
#pragma unroll
        for (int j = 0; j < 4; ++j) acc[i][j] = (f32x4)0.0f;

    const int lane = tid & 63;
    const int wv   = tid >> 6;
    const char* a_src[4];
#pragma unroll
    for (int i = 0; i < 4; ++i) {
        int lrow  = wv*32 + i*8 + (lane >> 3);
        int garow = off + m0 + lrow; if (garow > NPAIR-1) garow = NPAIR-1;
        a_src[i] = (const char*)h + (size_t)garow*(IDIM*2) + (lane & 7)*16;
    }
    const int base7 = (off + m0) & 7;

    const int wm = (wv >> 1) * 64, wn = (wv & 1) * 64;
    const int lr = lane & 15, lk = lane >> 4;

    const int NT = IDIM/64;    // 44
    const int NG = IDIM/128;   // 22
    const int NJSTEP = 44*128;
    const int SSTEP  = 16*(IDIM/128);
    const size_t bwo0 = ((size_t)(e*(DDIM/16) + ((n0 + wn) >> 4)))*(size_t)NJSTEP
                      + (size_t)(lr*8 + lk*2);
    const size_t swo0 = ((size_t)e*DDIM + (n0 + wn + lr))*(IDIM/128);

    uint2v pX[4], pY[4];
    float sC[4], cC[4], sN[4], cN[4];

    ISSUE_A(0, 0);
    LOADB(pX, 0);
    LOADS(sC, cC, 0);
    for (int kt = 0; kt < NT; kt += 2) STEP_PAIR(kt);
    __syncthreads();   // drain trailing prefetch DMA before LDS dealloc

#pragma unroll
    for (int mi = 0; mi < 4; ++mi)
#pragma unroll
        for (int nj = 0; nj < 4; ++nj) {
            f32x4 v = acc[mi][nj];
            int col = n0 + wn + nj*16 + lr;
#pragma unroll
            for (int r = 0; r < 4; ++r) {
                int row = wm + mi*16 + lk*4 + r;
                if (m0 + row < cnt) {
                    int p = meta[64 + off + m0 + row];
                    float w = tw[p];
                    yp[(size_t)p*DDIM + col] = v[r] * w;
                }
            }
        }
}

// ---------------- combine: out[t] = yp[2t] + yp[2t+1] ------------------------
__global__ void combine_kernel(const float* __restrict__ yp, float* __restrict__ out) {
    const int i = blockIdx.x * 256 + threadIdx.x;      // float4 index
    const int t = i >> 9, d = i & 511;
    const f32x4* a = (const f32x4*)yp;
    f32x4 va = a[(size_t)(t*2)*512 + d];
    f32x4 vb = a[(size_t)(t*2+1)*512 + d];
    ((f32x4*)out)[i] = va + vb;
}

extern "C" void kernel_launch(void* const* d_in, const int* in_sizes, int n_in,
                              void* d_out, int out_size, void* d_ws, size_t ws_size,
                              hipStream_t stream) {
    const float* x    = (const float*)d_in[0];
    const int*   ids  = (const int*)d_in[1];
    const float* tw   = (const float*)d_in[2];
    const int*   w13p = (const int*)d_in[3];
    const float* w13s = (const float*)d_in[4];
    const float* w13z = (const float*)d_in[5];
    const int*   w2p  = (const int*)d_in[6];
    const float* w2s  = (const float*)d_in[7];
    const float* w2z  = (const float*)d_in[8];
    float* out = (float*)d_out;

    char* ws = (char*)d_ws;
    int* meta = (int*)ws;
    unsigned short* Aall = (unsigned short*)(ws + OFF_A);
    unsigned short* gu   = (unsigned short*)(ws + OFF_GU);
    unsigned short* h    = (unsigned short*)(ws + OFF_H);
    float* yp            = (float*)(ws + OFF_YP);
    // dense-weight overlays (lifetimes disjoint with the regions they borrow)
    unsigned int* W13d = (unsigned int*)(ws + OFF_H);
    unsigned int* W2d  = (unsigned int*)(ws + OFF_GU);

    route_kernel<<<1, 256, 0, stream>>>(ids, meta);
    gather_kernel<<<NPAIR, 256, 0, stream>>>(x, meta, Aall);
    repackB_kernel<<<(int)(W13_DWORDS/1024), 256, 0, stream>>>(
        w13p, W13d, GU_N/16, DDIM/64, DDIM/2, (int)(W13_DWORDS/4));
    gemm1_kernel<<<dim3(GU_N/128, NPAIR/128, NE), 256, 0, stream>>>(
        Aall, W13d, w13s, w13z, meta, gu);
    act_kernel<<<NPAIR, 256, 0, stream>>>(gu, h);
    repackB_kernel<<<(int)(W2_DWORDS/1024), 256, 0, stream>>>(
        w2p, W2d, DDIM/16, IDIM/64, IDIM/2, (int)(W2_DWORDS/4));
    gemm2_kernel<<<dim3(DDIM/128, NPAIR/128, NE), 256, 0, stream>>>(
        h, W2d, w2s, w2z, tw, meta, yp);
    combine_kernel<<<(T_TOK*DDIM/4)/256, 256, 0, stream>>>(yp, out);
}

// Round 12
// 376.047 us; speedup vs baseline: 1.8129x; 1.2502x over previous
//
#include <hip/hip_runtime.h>
#include <hip/hip_bf16.h>

// Problem constants (fixed by setup_inputs)
#define T_TOK 2048
#define DDIM  2048
#define IDIM  2816
#define NE    8
#define NPAIR (T_TOK*2)      // 4096 (token, k) pairs
#define GU_N  (2*IDIM)       // 5632

typedef __bf16  bf16x8 __attribute__((ext_vector_type(8)));
typedef float   f32x4  __attribute__((ext_vector_type(4)));
typedef int     int4v  __attribute__((ext_vector_type(4)));
typedef unsigned int uint4v __attribute__((ext_vector_type(4)));

// ws layout (bytes)
#define OFF_A   (64*1024)
#define OFF_GU  (OFF_A  + (size_t)NPAIR*DDIM*2)   // A_all: 16 MB bf16 (pre-swizzled)
#define OFF_H   (OFF_GU + (size_t)NPAIR*GU_N*2)   // gate_up: 46 MB bf16 (linear)
#define OFF_YP  (OFF_H  + (size_t)NPAIR*IDIM*2)   // h: 23 MB bf16 (pre-swizzled)
// yp: 32 MB f32 after that; total ~119 MB
// Dense-weight overlays (no extra ws): W13d (46.14 MB) at OFF_H — dead once
// gemm1 finishes, before act writes h / gemm2 writes yp over it.
// W2d (23.07 MB) at OFF_GU — written after act (gu dead), read by gemm2.
#define W13_DWORDS (NE*(size_t)GU_N*(DDIM/8))   // 11,534,336
#define W2_DWORDS  (NE*(size_t)DDIM*(IDIM/8))   //  5,767,168

__device__ __forceinline__ unsigned short f2bf(float f) {
    __hip_bfloat16 h = __float2bfloat16(f);
    return __builtin_bit_cast(unsigned short, h);
}
__device__ __forceinline__ float bf2f(unsigned short u) {
    unsigned int x = ((unsigned int)u) << 16;
    return __builtin_bit_cast(float, x);
}
__device__ __forceinline__ unsigned int pack2bf(float lo, float hi) {
    return ((unsigned int)f2bf(hi) << 16) | (unsigned int)f2bf(lo);
}
// async global->LDS, 16B per lane; LDS dest must be wave-uniform-base + lane*16
__device__ __forceinline__ void gload_lds16(const void* g, void* l) {
    __builtin_amdgcn_global_load_lds(
        (const __attribute__((address_space(1))) void*)g,
        (__attribute__((address_space(3))) void*)l, 16, 0, 0);
}

// ---------------- routing: stable compaction of 4096 pairs by expert ---------
// meta: [0..7]=cnt, [8..15]=off (exclusive prefix), [64..64+4095]=list (pair idx)
__global__ void route_kernel(const int* __restrict__ ids, int* __restrict__ meta) {
    __shared__ int histL[NE][256];
    __shared__ int totals[NE];
    __shared__ int offsS[NE];
    const int tid = threadIdx.x;
    for (int e = 0; e < NE; ++e) histL[e][tid] = 0;
    for (int j = 0; j < 16; ++j) {
        int id = ids[tid*16 + j];
        histL[id][tid]++;
    }
    __syncthreads();
    if (tid < NE) {
        int run = 0;
        for (int i = 0; i < 256; ++i) { int v = histL[tid][i]; histL[tid][i] = run; run += v; }
        totals[tid] = run;
    }
    __syncthreads();
    if (tid == 0) {
        int run = 0;
        for (int e = 0; e < NE; ++e) {
            offsS[e] = run;
            meta[e] = totals[e];
            meta[8+e] = run;
            run += totals[e];
        }
    }
    __syncthreads();
    for (int j = 0; j < 16; ++j) {
        int p = tid*16 + j;
        int id = ids[p];
        int local = histL[id][tid];
        histL[id][tid] = local + 1;
        meta[64 + offsS[id] + local] = p;
    }
}

// ---------------- gather: x rows -> compact PRE-SWIZZLED bf16 A matrix -------
// logical col-byte cb of row r stored at (cb&~127) | ((cb&127) ^ ((r&7)<<4))
__global__ void gather_kernel(const float* __restrict__ x, const int* __restrict__ meta,
                              unsigned short* __restrict__ Aall) {
    const int r = blockIdx.x;
    const int p = meta[64 + r];
    const int t = p >> 1;
    const int c = threadIdx.x * 8;
    const float4* src = (const float4*)(x + (size_t)t*DDIM + c);
    float4 f0 = src[0], f1 = src[1];
    unsigned short o[8];
    o[0]=f2bf(f0.x); o[1]=f2bf(f0.y); o[2]=f2bf(f0.z); o[3]=f2bf(f0.w);
    o[4]=f2bf(f1.x); o[5]=f2bf(f1.y); o[6]=f2bf(f1.z); o[7]=f2bf(f1.w);
    int cb  = c * 2;
    int cbs = (cb & ~127) | ((cb & 127) ^ ((r & 7) << 4));
    *(uint4v*)((char*)Aall + (size_t)r*(DDIM*2) + cbs) = *(uint4v*)o;
}

// ---------------- repack: 4x int32 (2 nibbles each) -> 1 uint32 (8 nibbles) --
// dense word i covers the same k-range as src ints [4i, 4i+4); byte b of the
// dense word == (src[4i+b] & 0xFF) (lo nibble = even k, hi nibble = odd k) —
// exactly the old per-int layout, so GEMM DEQ keeps the same weight order.
// 4 dense words per thread: 64B coalesced in, 16B dwordx4 out.
__global__ void repack_kernel(const int* __restrict__ src,
                              unsigned int* __restrict__ dst, int nwords4) {
    const int i4 = blockIdx.x * 256 + threadIdx.x;
    if (i4 >= nwords4) return;
    const int4v* s = (const int4v*)(src + (size_t)i4*16);
    uint4v d;
#pragma unroll
    for (int q = 0; q < 4; ++q) {
        int4v p = s[q];
        d[q] = ((unsigned int)p[0] & 0xFFu)
             | (((unsigned int)p[1] & 0xFFu) << 8)
             | (((unsigned int)p[2] & 0xFFu) << 16)
             | (((unsigned int)p[3] & 0xFFu) << 24);
    }
    *(uint4v*)(dst + (size_t)i4*4) = d;
}

// ============ pipelined dequant-GEMM macros (shared by gemm1/gemm2) ==========
// LOADB: ONE dwordx4 of dense-packed B (32 weights) + scale/zp for K-tile KT
#define LOADB(PK, SS, ZZ, KT)  do {                                        \
    PK = *(const uint4v*)(bgp + (size_t)(KT)*8);                           \
    int _g = (KT) >> 1;                                                    \
    SS = sp[_g]; ZZ = zp[_g];                                              \
} while (0)

// ISSUE_A: async-copy A K-slab KT into As[SEL] (linear copy of pre-swizzled rows)
#define ISSUE_A(SEL, KT) do {                                              \
    _Pragma("unroll")                                                      \
    for (int _i = 0; _i < 4; ++_i)                                         \
        gload_lds16(a_src[_i] + (size_t)(KT)*128,                          \
                    (char*)&As[SEL][0] + wv*4096 + _i*1024 + lane*16);     \
} while (0)

// DEQ: nibble-plane split -> byte extracts. (plane >> 8j) & 0xFF folds to
// single-op v_cvt_f32_ubyte{0..3}. Arithmetic is bit-identical to R5.
#define DEQ(PK, SS, ZZ, BWP) do {                                          \
    float _s = SS, _c = -(ZZ)*(SS);                                        \
    _Pragma("unroll")                                                      \
    for (int _q = 0; _q < 4; ++_q) {                                       \
        unsigned int _w  = PK[_q];                                         \
        unsigned int _lo = _w & 0x0F0F0F0Fu;                               \
        unsigned int _hi = (_w >> 4) & 0x0F0F0F0Fu;                        \
        _Pragma("unroll")                                                  \
        for (int _j = 0; _j < 4; ++_j) {                                   \
            float _flo = (float)((_lo >> (8*_j)) & 0xFFu);                 \
            float _fhi = (float)((_hi >> (8*_j)) & 0xFFu);                 \
            BWP[_q*4 + _j] = pack2bf(fmaf(_flo, _s, _c),                   \
                                     fmaf(_fhi, _s, _c));                  \
        }                                                                  \
    }                                                                      \
} while (0)

#define WRITE_BS(BWP) do {                                                 \
    _Pragma("unroll")                                                      \
    for (int _q = 0; _q < 4; ++_q) {                                       \
        int _cb  = ahalf*64 + _q*16;                                       \
        int _cbs = _cb ^ swzB;                                             \
        *(uint4v*)(&Bs[arow*64 + (_cbs >> 1)]) = *(uint4v*)(&BWP[_q*4]);   \
    }                                                                      \
} while (0)

// MFMA_STEP: ds_read frags (A xor uses global-row parity base7+row) and accumulate
#define MFMA_STEP(SEL) do {                                                \
    _Pragma("unroll")                                                      \
    for (int _kk = 0; _kk < 2; ++_kk) {                                    \
        bf16x8 _af[4], _bf[4];                                             \
        const int _kbyte = _kk*64 + lk*16;                                 \
        _Pragma("unroll")                                                  \
        for (int _mi = 0; _mi < 4; ++_mi) {                                \
            int _row = wm + _mi*16 + lr;                                   \
            int _b = _kbyte ^ (((_row + base7) & 7) << 4);                 \
            _af[_mi] = *(const bf16x8*)(&As[SEL][_row*64 + (_b >> 1)]);    \
        }                                                                  \
        _Pragma("unroll")                                                  \
        for (int _nj = 0; _nj < 4; ++_nj) {                                \
            int _row = wn + _nj*16 + lr;                                   \
            int _b = _kbyte ^ ((_row & 7) << 4);                           \
            _bf[_nj] = *(const bf16x8*)(&Bs[_row*64 + (_b >> 1)]);         \
        }                                                                  \
        _Pragma("unroll")                                                  \
        for (int _mi = 0; _mi < 4; ++_mi)                                  \
            _Pragma("unroll")                                              \
            for (int _nj = 0; _nj < 4; ++_nj)                              \
                acc[_mi][_nj] = __builtin_amdgcn_mfma_f32_16x16x32_bf16(   \
                    _af[_mi], _bf[_nj], acc[_mi][_nj], 0, 0, 0);           \
    }                                                                      \
} while (0)

// One K-step (the session-proven schedule — best of all 8 structures tested):
// barrier1; issue t+1 (A async->LDS, B->regs); dequant+commit t (the DEQ
// phase ages the in-flight loads so barrier2's implicit vmcnt(0) drain is
// nearly free — R8 proved removing DEQ exposes raw latency); barrier2; MFMA t.
#define STEP(T, SELC, SELN, PKC, sC, zC, PKN, sN, zN) do {                 \
    if ((T) > 0) __syncthreads();                                          \
    int _ktn = (T)+1 < NT ? (T)+1 : NT-1;                                  \
    ISSUE_A(SELN, _ktn);                                                   \
    LOADB(PKN, sN, zN, _ktn);                                              \
    unsigned int _bw[16];                                                  \
    DEQ(PKC, sC, zC, _bw);                                                 \
    WRITE_BS(_bw);                                                         \
    __syncthreads();                                                       \
    MFMA_STEP(SELC);                                                       \
} while (0)

// ---------------- GEMM1: A[4096,2048]bf16 x W13d[e]^T (dense int4) -----------
__launch_bounds__(256, 3)
__global__ void gemm1_kernel(const unsigned short* __restrict__ Aall,
                             const unsigned int* __restrict__ wd,
                             const float* __restrict__ wsc,
                             const float* __restrict__ wzp,
                             const int* __restrict__ meta,
                             unsigned short* __restrict__ gu) {
    const int e   = blockIdx.z;
    const int cnt = meta[e];
    const int m0  = blockIdx.y * 128;
    if (m0 >= cnt) return;
    const int off = meta[8 + e];
    const int n0  = blockIdx.x * 128;
    const int tid = threadIdx.x;

    __shared__ unsigned short As[2][128*64];
    __shared__ unsigned short Bs[128*64];

    f32x4 acc[4][4];
#pragma unroll
    for (int i = 0; i < 4; ++i)
#pragma unroll
        for (int j = 0; j < 4; ++j) acc[i][j] = (f32x4)0.0f;

    // B staging mapping (dense words: DDIM/8 = 256 per row; 8 per K-step)
    const int arow  = tid >> 1;
    const int ahalf = tid & 1;
    const int gbrow = n0 + arow;
    const unsigned int* bgp = wd + ((size_t)e*GU_N + gbrow)*(DDIM/8) + ahalf*4;
    const float* sp = wsc + ((size_t)e*GU_N + gbrow)*(DDIM/128);
    const float* zp = wzp + ((size_t)e*GU_N + gbrow)*(DDIM/128);
    const int swzB  = (arow & 7) << 4;

    // A async-copy mapping
    const int lane = tid & 63;
    const int wv   = tid >> 6;
    const char* a_src[4];
#pragma unroll
    for (int i = 0; i < 4; ++i) {
        int lrow  = wv*32 + i*8 + (lane >> 3);
        int garow = off + m0 + lrow; if (garow > NPAIR-1) garow = NPAIR-1;
        a_src[i] = (const char*)Aall + (size_t)garow*(DDIM*2) + (lane & 7)*16;
    }
    const int base7 = (off + m0) & 7;

    const int wm = (wv >> 1) * 64, wn = (wv & 1) * 64;
    const int lr = lane & 15, lk = lane >> 4;

    const int NT = DDIM/64;   // 32 (even)
    uint4v pkX, pkY;
    float sX, zX, sY, zY;

    ISSUE_A(0, 0);
    LOADB(pkX, sX, zX, 0);
    for (int kt = 0; kt < NT; kt += 2) {
        STEP(kt,   0, 1, pkX, sX, zX, pkY, sY, zY);
        STEP(kt+1, 1, 0, pkY, sY, zY, pkX, sX, zX);
    }

    // epilogue: C[m][n] lane map col=lane&15, row=(lane>>4)*4+reg (m89)
#pragma unroll
    for (int mi = 0; mi < 4; ++mi)
#pragma unroll
        for (int nj = 0; nj < 4; ++nj) {
            f32x4 v = acc[mi][nj];
            int col = n0 + wn + nj*16 + lr;
#pragma unroll
            for (int r = 0; r < 4; ++r) {
                int row = wm + mi*16 + lk*4 + r;
                if (m0 + row < cnt)
                    gu[(size_t)(off + m0 + row)*GU_N + col] = f2bf(v[r]);
            }
        }
}

// ---------------- activation: h = silu(g)*u, written PRE-SWIZZLED ------------
__global__ void act_kernel(const unsigned short* __restrict__ gu,
                           unsigned short* __restrict__ h) {
    const int r = blockIdx.x;
    for (int c = threadIdx.x; c < IDIM/8; c += 256) {
        uint4v g8 = *(const uint4v*)(&gu[(size_t)r*GU_N + c*8]);
        uint4v u8 = *(const uint4v*)(&gu[(size_t)r*GU_N + IDIM + c*8]);
        const unsigned short* gp = (const unsigned short*)&g8;
        const unsigned short* up = (const unsigned short*)&u8;
        unsigned short o[8];
#pragma unroll
        for (int j = 0; j < 8; ++j) {
            float g = bf2f(gp[j]), u = bf2f(up[j]);
            float sg = g / (1.0f + __expf(-g));
            o[j] = f2bf(sg * u);
        }
        int cb  = c * 16;
        int cbs = (cb & ~127) | ((cb & 127) ^ ((r & 7) << 4));
        *(uint4v*)((char*)h + (size_t)r*(IDIM*2) + cbs) = *(uint4v*)o;
    }
}

// ---------------- GEMM2: h[4096,2816]bf16 x W2d[e]^T (dense int4) ------------
__launch_bounds__(256, 3)
__global__ void gemm2_kernel(const unsigned short* __restrict__ h,
                             const unsigned int* __restrict__ wd,
                             const float* __restrict__ wsc,
                             const float* __restrict__ wzp,
                             const float* __restrict__ tw,
                             const int* __restrict__ meta,
                             float* __restrict__ yp) {
    const int e   = blockIdx.z;
    const int cnt = meta[e];
    const int m0  = blockIdx.y * 128;
    if (m0 >= cnt) return;
    const int off = meta[8 + e];
    const int n0  = blockIdx.x * 128;
    const int tid = threadIdx.x;

    __shared__ unsigned short As[2][128*64];
    __shared__ unsigned short Bs[128*64];

    f32x4 acc[4][4];
#pragma unroll
    for (int i = 0; i < 4; ++i)
#pragma unroll
        for (int j = 0; j < 4; ++j) acc[i][j] = (f32x4)0.0f;

    const int arow  = tid >> 1;
    const int ahalf = tid & 1;
    const int gbrow = n0 + arow;
    const unsigned int* bgp = wd + ((size_t)e*DDIM + gbrow)*(IDIM/8) + ahalf*4;
    const float* sp = wsc + ((size_t)e*DDIM + gbrow)*(IDIM/128);
    const float* zp = wzp + ((size_t)e*DDIM + gbrow)*(IDIM/128);
    const int swzB  = (arow & 7) << 4;

    const int lane = tid & 63;
    const int wv   = tid >> 6;
    const char* a_src[4];
#pragma unroll
    for (int i = 0; i < 4; ++i) {
        int lrow  = wv*32 + i*8 + (lane >> 3);
        int garow = off + m0 + lrow; if (garow > NPAIR-1) garow = NPAIR-1;
        a_src[i] = (const char*)h + (size_t)garow*(IDIM*2) + (lane & 7)*16;
    }
    const int base7 = (off + m0) & 7;

    const int wm = (wv >> 1) * 64, wn = (wv & 1) * 64;
    const int lr = lane & 15, lk = lane >> 4;

    const int NT = IDIM/64;   // 44 (even)
    uint4v pkX, pkY;
    float sX, zX, sY, zY;

    ISSUE_A(0, 0);
    LOADB(pkX, sX, zX, 0);
    for (int kt = 0; kt < NT; kt += 2) {
        STEP(kt,   0, 1, pkX, sX, zX, pkY, sY, zY);
        STEP(kt+1, 1, 0, pkY, sY, zY, pkX, sX, zX);
    }

#pragma unroll
    for (int mi = 0; mi < 4; ++mi)
#pragma unroll
        for (int nj = 0; nj < 4; ++nj) {
            f32x4 v = acc[mi][nj];
            int col = n0 + wn + nj*16 + lr;
#pragma unroll
            for (int r = 0; r < 4; ++r) {
                int row = wm + mi*16 + lk*4 + r;
                if (m0 + row < cnt) {
                    int p = meta[64 + off + m0 + row];
                    float w = tw[p];
                    yp[(size_t)p*DDIM + col] = v[r] * w;
                }
            }
        }
}

// ---------------- combine: out[t] = yp[2t] + yp[2t+1] ------------------------
__global__ void combine_kernel(const float* __restrict__ yp, float* __restrict__ out) {
    const int i = blockIdx.x * 256 + threadIdx.x;      // float4 index
    const int t = i >> 9, d = i & 511;
    const f32x4* a = (const f32x4*)yp;
    f32x4 va = a[(size_t)(t*2)*512 + d];
    f32x4 vb = a[(size_t)(t*2+1)*512 + d];
    ((f32x4*)out)[i] = va + vb;
}

extern "C" void kernel_launch(void* const* d_in, const int* in_sizes, int n_in,
                              void* d_out, int out_size, void* d_ws, size_t ws_size,
                              hipStream_t stream) {
    const float* x    = (const float*)d_in[0];
    const int*   ids  = (const int*)d_in[1];
    const float* tw   = (const float*)d_in[2];
    const int*   w13p = (const int*)d_in[3];
    const float* w13s = (const float*)d_in[4];
    const float* w13z = (const float*)d_in[5];
    const int*   w2p  = (const int*)d_in[6];
    const float* w2s  = (const float*)d_in[7];
    const float* w2z  = (const float*)d_in[8];
    float* out = (float*)d_out;

    char* ws = (char*)d_ws;
    int* meta = (int*)ws;
    unsigned short* Aall = (unsigned short*)(ws + OFF_A);
    unsigned short* gu   = (unsigned short*)(ws + OFF_GU);
    unsigned short* h    = (unsigned short*)(ws + OFF_H);
    float* yp            = (float*)(ws + OFF_YP);
    // dense-weight overlays (lifetimes disjoint with the regions they borrow)
    unsigned int* W13d = (unsigned int*)(ws + OFF_H);    // dead after gemm1
    unsigned int* W2d  = (unsigned int*)(ws + OFF_GU);   // written after act

    route_kernel<<<1, 256, 0, stream>>>(ids, meta);
    gather_kernel<<<NPAIR, 256, 0, stream>>>(x, meta, Aall);
    repack_kernel<<<(int)(W13_DWORDS/1024), 256, 0, stream>>>(w13p, W13d, (int)(W13_DWORDS/4));
    gemm1_kernel<<<dim3(GU_N/128, NPAIR/128, NE), 256, 0, stream>>>(Aall, W13d, w13s, w13z, meta, gu);
    act_kernel<<<NPAIR, 256, 0, stream>>>(gu, h);
    repack_kernel<<<(int)(W2_DWORDS/1024), 256, 0, stream>>>(w2p, W2d, (int)(W2_DWORDS/4));
    gemm2_kernel<<<dim3(DDIM/128, NPAIR/128, NE), 256, 0, stream>>>(h, W2d, w2s, w2z, tw, meta, yp);
    combine_kernel<<<(T_TOK*DDIM/4)/256, 256, 0, stream>>>(yp, out);
}

// Round 13
// 364.112 us; speedup vs baseline: 1.8723x; 1.0328x over previous
//
#include <hip/hip_runtime.h>
#include <hip/hip_bf16.h>

// Problem constants (fixed by setup_inputs)
#define T_TOK 2048
#define DDIM  2048
#define IDIM  2816
#define NE    8
#define NPAIR (T_TOK*2)      // 4096 (token, k) pairs
#define GU_N  (2*IDIM)       // 5632

typedef __bf16  bf16x8 __attribute__((ext_vector_type(8)));
typedef float   f32x4  __attribute__((ext_vector_type(4)));
typedef int     int4v  __attribute__((ext_vector_type(4)));
typedef unsigned int uint4v __attribute__((ext_vector_type(4)));

// ws layout (bytes)
#define OFF_A   (64*1024)
#define OFF_GU  (OFF_A  + (size_t)NPAIR*DDIM*2)   // 46.14 MB region (weights overlay)
#define OFF_H   (OFF_GU + (size_t)NPAIR*GU_N*2)   // h: 23 MB bf16 (pre-swizzled)
#define OFF_YP  (OFF_H  + (size_t)NPAIR*IDIM*2)   // yp: 32 MB f32
// act is fused into gemm1 (in-register silu), so the old gu buffer is gone.
// Weight overlays (stream-serial lifetimes, no region conflicts):
//   W13d (46.14 MB) at OFF_GU: written by repack13, read by gemm1 (which
//     writes h at OFF_H — disjoint). Dead after gemm1.
//   W2d  (23.07 MB) at OFF_GU: written by repack2 AFTER gemm1 (over dead
//     W13d), read by gemm2 (writes yp at OFF_YP — disjoint).
#define W13_DWORDS (NE*(size_t)GU_N*(DDIM/8))   // 11,534,336
#define W2_DWORDS  (NE*(size_t)DDIM*(IDIM/8))   //  5,767,168

__device__ __forceinline__ unsigned short f2bf(float f) {
    __hip_bfloat16 h = __float2bfloat16(f);
    return __builtin_bit_cast(unsigned short, h);
}
__device__ __forceinline__ float bf2f(unsigned short u) {
    unsigned int x = ((unsigned int)u) << 16;
    return __builtin_bit_cast(float, x);
}
__device__ __forceinline__ unsigned int pack2bf(float lo, float hi) {
    return ((unsigned int)f2bf(hi) << 16) | (unsigned int)f2bf(lo);
}
// async global->LDS, 16B per lane; LDS dest must be wave-uniform-base + lane*16
__device__ __forceinline__ void gload_lds16(const void* g, void* l) {
    __builtin_amdgcn_global_load_lds(
        (const __attribute__((address_space(1))) void*)g,
        (__attribute__((address_space(3))) void*)l, 16, 0, 0);
}

// ---------------- routing: stable compaction of 4096 pairs by expert ---------
// meta: [0..7]=cnt, [8..15]=off (exclusive prefix), [64..64+4095]=list (pair idx)
__global__ void route_kernel(const int* __restrict__ ids, int* __restrict__ meta) {
    __shared__ int histL[NE][256];
    __shared__ int totals[NE];
    __shared__ int offsS[NE];
    const int tid = threadIdx.x;
    for (int e = 0; e < NE; ++e) histL[e][tid] = 0;
    for (int j = 0; j < 16; ++j) {
        int id = ids[tid*16 + j];
        histL[id][tid]++;
    }
    __syncthreads();
    if (tid < NE) {
        int run = 0;
        for (int i = 0; i < 256; ++i) { int v = histL[tid][i]; histL[tid][i] = run; run += v; }
        totals[tid] = run;
    }
    __syncthreads();
    if (tid == 0) {
        int run = 0;
        for (int e = 0; e < NE; ++e) {
            offsS[e] = run;
            meta[e] = totals[e];
            meta[8+e] = run;
            run += totals[e];
        }
    }
    __syncthreads();
    for (int j = 0; j < 16; ++j) {
        int p = tid*16 + j;
        int id = ids[p];
        int local = histL[id][tid];
        histL[id][tid] = local + 1;
        meta[64 + offsS[id] + local] = p;
    }
}

// ---------------- gather: x rows -> compact PRE-SWIZZLED bf16 A matrix -------
// logical col-byte cb of row r stored at (cb&~127) | ((cb&127) ^ ((r&7)<<4))
__global__ void gather_kernel(const float* __restrict__ x, const int* __restrict__ meta,
                              unsigned short* __restrict__ Aall) {
    const int r = blockIdx.x;
    const int p = meta[64 + r];
    const int t = p >> 1;
    const int c = threadIdx.x * 8;
    const float4* src = (const float4*)(x + (size_t)t*DDIM + c);
    float4 f0 = src[0], f1 = src[1];
    unsigned short o[8];
    o[0]=f2bf(f0.x); o[1]=f2bf(f0.y); o[2]=f2bf(f0.z); o[3]=f2bf(f0.w);
    o[4]=f2bf(f1.x); o[5]=f2bf(f1.y); o[6]=f2bf(f1.z); o[7]=f2bf(f1.w);
    int cb  = c * 2;
    int cbs = (cb & ~127) | ((cb & 127) ^ ((r & 7) << 4));
    *(uint4v*)((char*)Aall + (size_t)r*(DDIM*2) + cbs) = *(uint4v*)o;
}

// ---------------- repack: 4x int32 (2 nibbles each) -> 1 uint32 (8 nibbles) --
// dense word i covers the same k-range as src ints [4i, 4i+4); byte b of the
// dense word == (src[4i+b] & 0xFF) — the GEMM DEQ keeps the same weight order.
// 4 dense words per thread: 64B coalesced in, 16B dwordx4 out.
__global__ void repack_kernel(const int* __restrict__ src,
                              unsigned int* __restrict__ dst, int nwords4) {
    const int i4 = blockIdx.x * 256 + threadIdx.x;
    if (i4 >= nwords4) return;
    const int4v* s = (const int4v*)(src + (size_t)i4*16);
    uint4v d;
#pragma unroll
    for (int q = 0; q < 4; ++q) {
        int4v p = s[q];
        d[q] = ((unsigned int)p[0] & 0xFFu)
             | (((unsigned int)p[1] & 0xFFu) << 8)
             | (((unsigned int)p[2] & 0xFFu) << 16)
             | (((unsigned int)p[3] & 0xFFu) << 24);
    }
    *(uint4v*)(dst + (size_t)i4*4) = d;
}

// ============ pipelined dequant-GEMM macros (shared by gemm1/gemm2) ==========
// LOADB: ONE dwordx4 of dense-packed B (32 weights) + scale/zp for K-tile KT
#define LOADB(PK, SS, ZZ, KT)  do {                                        \
    PK = *(const uint4v*)(bgp + (size_t)(KT)*8);                           \
    int _g = (KT) >> 1;                                                    \
    SS = sp[_g]; ZZ = zp[_g];                                              \
} while (0)

// ISSUE_A: async-copy A K-slab KT into As[SEL] (linear copy of pre-swizzled rows)
#define ISSUE_A(SEL, KT) do {                                              \
    _Pragma("unroll")                                                      \
    for (int _i = 0; _i < 4; ++_i)                                         \
        gload_lds16(a_src[_i] + (size_t)(KT)*128,                          \
                    (char*)&As[SEL][0] + wv*4096 + _i*1024 + lane*16);     \
} while (0)

// DEQ: nibble-plane split -> byte extracts (v_cvt_f32_ubyte candidates)
#define DEQ(PK, SS, ZZ, BWP) do {                                          \
    float _s = SS, _c = -(ZZ)*(SS);                                        \
    _Pragma("unroll")                                                      \
    for (int _q = 0; _q < 4; ++_q) {                                       \
        unsigned int _w  = PK[_q];                                         \
        unsigned int _lo = _w & 0x0F0F0F0Fu;                               \
        unsigned int _hi = (_w >> 4) & 0x0F0F0F0Fu;                        \
        _Pragma("unroll")                                                  \
        for (int _j = 0; _j < 4; ++_j) {                                   \
            float _flo = (float)((_lo >> (8*_j)) & 0xFFu);                 \
            float _fhi = (float)((_hi >> (8*_j)) & 0xFFu);                 \
            BWP[_q*4 + _j] = pack2bf(fmaf(_flo, _s, _c),                   \
                                     fmaf(_fhi, _s, _c));                  \
        }                                                                  \
    }                                                                      \
} while (0)

#define WRITE_BS(BWP) do {                                                 \
    _Pragma("unroll")                                                      \
    for (int _q = 0; _q < 4; ++_q) {                                       \
        int _cb  = ahalf*64 + _q*16;                                       \
        int _cbs = _cb ^ swzB;                                             \
        *(uint4v*)(&Bs[arow*64 + (_cbs >> 1)]) = *(uint4v*)(&BWP[_q*4]);   \
    }                                                                      \
} while (0)

// MFMA_STEP: ds_read frags (A xor uses global-row parity base7+row) and accumulate
#define MFMA_STEP(SEL) do {                                                \
    _Pragma("unroll")                                                      \
    for (int _kk = 0; _kk < 2; ++_kk) {                                    \
        bf16x8 _af[4], _bf[4];                                             \
        const int _kbyte = _kk*64 + lk*16;                                 \
        _Pragma("unroll")                                                  \
        for (int _mi = 0; _mi < 4; ++_mi) {                                \
            int _row = wm + _mi*16 + lr;                                   \
            int _b = _kbyte ^ (((_row + base7) & 7) << 4);                 \
            _af[_mi] = *(const bf16x8*)(&As[SEL][_row*64 + (_b >> 1)]);    \
        }                                                                  \
        _Pragma("unroll")                                                  \
        for (int _nj = 0; _nj < 4; ++_nj) {                                \
            int _row = wn + _nj*16 + lr;                                   \
            int _b = _kbyte ^ ((_row & 7) << 4);                           \
            _bf[_nj] = *(const bf16x8*)(&Bs[_row*64 + (_b >> 1)]);         \
        }                                                                  \
        _Pragma("unroll")                                                  \
        for (int _mi = 0; _mi < 4; ++_mi)                                  \
            _Pragma("unroll")                                              \
            for (int _nj = 0; _nj < 4; ++_nj)                              \
                acc[_mi][_nj] = __builtin_amdgcn_mfma_f32_16x16x32_bf16(   \
                    _af[_mi], _bf[_nj], acc[_mi][_nj], 0, 0, 0);           \
    }                                                                      \
} while (0)

// One K-step (the session-proven schedule — best of all structures tested):
// barrier1; issue t+1 (A async->LDS, B->regs); dequant+commit t (the DEQ
// phase ages the in-flight loads so barrier2's implicit vmcnt(0) drain is
// nearly free — R8 proved removing DEQ exposes raw latency); barrier2; MFMA t.
#define STEP(T, SELC, SELN, PKC, sC, zC, PKN, sN, zN) do {                 \
    if ((T) > 0) __syncthreads();                                          \
    int _ktn = (T)+1 < NT ? (T)+1 : NT-1;                                  \
    ISSUE_A(SELN, _ktn);                                                   \
    LOADB(PKN, sN, zN, _ktn);                                              \
    unsigned int _bw[16];                                                  \
    DEQ(PKC, sC, zC, _bw);                                                 \
    WRITE_BS(_bw);                                                         \
    __syncthreads();                                                       \
    MFMA_STEP(SELC);                                                       \
} while (0)

// ---------------- GEMM1 (act fused IN-REGISTER): writes h directly ----------
// B-row interleave: Bs row r holds global B-row
//   is_up(r) ? IDIM + n0h + hcl(r) : n0h + hcl(r)
// with hcl = (r>>5)*16 + (r&15), is_up = (r>>4)&1.  Every wave's nj tiles then
// pair up: acc[mi][2c] = gate, acc[mi][2c+1] = up for the SAME h-columns in
// the SAME thread -> silu(g)*u on registers. No LDS exchange (R7's failure),
// no extra barriers, same occupancy, same K-loop as the proven R12 kernel.
__launch_bounds__(256, 3)
__global__ void gemm1_kernel(const unsigned short* __restrict__ Aall,
                             const unsigned int* __restrict__ wd,
                             const float* __restrict__ wsc,
                             const float* __restrict__ wzp,
                             const int* __restrict__ meta,
                             unsigned short* __restrict__ h) {
    const int e   = blockIdx.z;
    const int cnt = meta[e];
    const int m0  = blockIdx.y * 128;
    if (m0 >= cnt) return;
    const int off = meta[8 + e];
    const int n0h = blockIdx.x * 64;      // h-column base (64 h-cols per block)
    const int tid = threadIdx.x;

    __shared__ unsigned short As[2][128*64];
    __shared__ unsigned short Bs[128*64];

    f32x4 acc[4][4];
#pragma unroll
    for (int i = 0; i < 4; ++i)
#pragma unroll
        for (int j = 0; j < 4; ++j) acc[i][j] = (f32x4)0.0f;

    // B staging mapping (interleaved gate/up rows; dense words 256 per row)
    const int arow  = tid >> 1;
    const int ahalf = tid & 1;
    const int hcl   = ((arow >> 5) << 4) + (arow & 15);   // 0..63
    const int is_up = (arow >> 4) & 1;
    const int gbrow = is_up ? (IDIM + n0h + hcl) : (n0h + hcl);
    const unsigned int* bgp = wd + ((size_t)e*GU_N + gbrow)*(DDIM/8) + ahalf*4;
    const float* sp = wsc + ((size_t)e*GU_N + gbrow)*(DDIM/128);
    const float* zp = wzp + ((size_t)e*GU_N + gbrow)*(DDIM/128);
    const int swzB  = (arow & 7) << 4;    // keyed on LDS row — matches MFMA read

    // A async-copy mapping
    const int lane = tid & 63;
    const int wv   = tid >> 6;
    const char* a_src[4];
#pragma unroll
    for (int i = 0; i < 4; ++i) {
        int lrow  = wv*32 + i*8 + (lane >> 3);
        int garow = off + m0 + lrow; if (garow > NPAIR-1) garow = NPAIR-1;
        a_src[i] = (const char*)Aall + (size_t)garow*(DDIM*2) + (lane & 7)*16;
    }
    const int base7 = (off + m0) & 7;

    const int wm = (wv >> 1) * 64, wn = (wv & 1) * 64;
    const int lr = lane & 15, lk = lane >> 4;

    const int NT = DDIM/64;   // 32 (even)
    uint4v pkX, pkY;
    float sX, zX, sY, zY;

    ISSUE_A(0, 0);
    LOADB(pkX, sX, zX, 0);
    for (int kt = 0; kt < NT; kt += 2) {
        STEP(kt,   0, 1, pkX, sX, zX, pkY, sY, zY);
        STEP(kt+1, 1, 0, pkY, sY, zY, pkX, sX, zX);
    }

    // fused epilogue: h[grow][col] = silu(g)*u, written with gemm2's pre-swizzle
    // nj tile -> Bs rows wn+nj*16+lr -> gate iff nj even, h-col
    // = n0h + ((wn>>5) + (nj>>1))*16 + lr.  C lane map: col=lane&15,
    // row=(lane>>4)*4+reg (m89).
#pragma unroll
    for (int mi = 0; mi < 4; ++mi)
#pragma unroll
        for (int cp = 0; cp < 2; ++cp) {
            f32x4 g = acc[mi][cp*2];
            f32x4 u = acc[mi][cp*2 + 1];
            int col = n0h + ((wn >> 5) + cp)*16 + lr;
            int cb  = col * 2;
#pragma unroll
            for (int r = 0; r < 4; ++r) {
                int row = wm + mi*16 + lk*4 + r;
                if (m0 + row < cnt) {
                    int grow = off + m0 + row;
                    float gg = g[r];
                    float sg = gg / (1.0f + __expf(-gg));
                    int cbs = (cb & ~127) | ((cb & 127) ^ ((grow & 7) << 4));
                    *(unsigned short*)((char*)h + (size_t)grow*(IDIM*2) + cbs)
                        = f2bf(sg * u[r]);
                }
            }
        }
}

// ---------------- GEMM2: h[4096,2816]bf16 x W2d[e]^T (dense int4) ------------
__launch_bounds__(256, 3)
__global__ void gemm2_kernel(const unsigned short* __restrict__ h,
                             const unsigned int* __restrict__ wd,
                             const float* __restrict__ wsc,
                             const float* __restrict__ wzp,
                             const float* __restrict__ tw,
                             const int* __restrict__ meta,
                             float* __restrict__ yp) {
    const int e   = blockIdx.z;
    const int cnt = meta[e];
    const int m0  = blockIdx.y * 128;
    if (m0 >= cnt) return;
    const int off = meta[8 + e];
    const int n0  = blockIdx.x * 128;
    const int tid = threadIdx.x;

    __shared__ unsigned short As[2][128*64];
    __shared__ unsigned short Bs[128*64];

    f32x4 acc[4][4];
#pragma unroll
    for (int i = 0; i < 4; ++i)
#pragma unroll
        for (int j = 0; j < 4; ++j) acc[i][j] = (f32x4)0.0f;

    const int arow  = tid >> 1;
    const int ahalf = tid & 1;
    const int gbrow = n0 + arow;
    const unsigned int* bgp = wd + ((size_t)e*DDIM + gbrow)*(IDIM/8) + ahalf*4;
    const float* sp = wsc + ((size_t)e*DDIM + gbrow)*(IDIM/128);
    const float* zp = wzp + ((size_t)e*DDIM + gbrow)*(IDIM/128);
    const int swzB  = (arow & 7) << 4;

    const int lane = tid & 63;
    const int wv   = tid >> 6;
    const char* a_src[4];
#pragma unroll
    for (int i = 0; i < 4; ++i) {
        int lrow  = wv*32 + i*8 + (lane >> 3);
        int garow = off + m0 + lrow; if (garow > NPAIR-1) garow = NPAIR-1;
        a_src[i] = (const char*)h + (size_t)garow*(IDIM*2) + (lane & 7)*16;
    }
    const int base7 = (off + m0) & 7;

    const int wm = (wv >> 1) * 64, wn = (wv & 1) * 64;
    const int lr = lane & 15, lk = lane >> 4;

    const int NT = IDIM/64;   // 44 (even)
    uint4v pkX, pkY;
    float sX, zX, sY, zY;

    ISSUE_A(0, 0);
    LOADB(pkX, sX, zX, 0);
    for (int kt = 0; kt < NT; kt += 2) {
        STEP(kt,   0, 1, pkX, sX, zX, pkY, sY, zY);
        STEP(kt+1, 1, 0, pkY, sY, zY, pkX, sX, zX);
    }

#pragma unroll
    for (int mi = 0; mi < 4; ++mi)
#pragma unroll
        for (int nj = 0; nj < 4; ++nj) {
            f32x4 v = acc[mi][nj];
            int col = n0 + wn + nj*16 + lr;
#pragma unroll
            for (int r = 0; r < 4; ++r) {
                int row = wm + mi*16 + lk*4 + r;
                if (m0 + row < cnt) {
                    int p = meta[64 + off + m0 + row];
                    float w = tw[p];
                    yp[(size_t)p*DDIM + col] = v[r] * w;
                }
            }
        }
}

// ---------------- combine: out[t] = yp[2t] + yp[2t+1] ------------------------
__global__ void combine_kernel(const float* __restrict__ yp, float* __restrict__ out) {
    const int i = blockIdx.x * 256 + threadIdx.x;      // float4 index
    const int t = i >> 9, d = i & 511;
    const f32x4* a = (const f32x4*)yp;
    f32x4 va = a[(size_t)(t*2)*512 + d];
    f32x4 vb = a[(size_t)(t*2+1)*512 + d];
    ((f32x4*)out)[i] = va + vb;
}

extern "C" void kernel_launch(void* const* d_in, const int* in_sizes, int n_in,
                              void* d_out, int out_size, void* d_ws, size_t ws_size,
                              hipStream_t stream) {
    const float* x    = (const float*)d_in[0];
    const int*   ids  = (const int*)d_in[1];
    const float* tw   = (const float*)d_in[2];
    const int*   w13p = (const int*)d_in[3];
    const float* w13s = (const float*)d_in[4];
    const float* w13z = (const float*)d_in[5];
    const int*   w2p  = (const int*)d_in[6];
    const float* w2s  = (const float*)d_in[7];
    const float* w2z  = (const float*)d_in[8];
    float* out = (float*)d_out;

    char* ws = (char*)d_ws;
    int* meta = (int*)ws;
    unsigned short* Aall = (unsigned short*)(ws + OFF_A);
    unsigned short* h    = (unsigned short*)(ws + OFF_H);
    float* yp            = (float*)(ws + OFF_YP);
    // weight overlays: both in the old gu region (46.14 MB), serial lifetimes
    unsigned int* W13d = (unsigned int*)(ws + OFF_GU);   // live: repack13..gemm1
    unsigned int* W2d  = (unsigned int*)(ws + OFF_GU);   // live: repack2..gemm2

    route_kernel<<<1, 256, 0, stream>>>(ids, meta);
    gather_kernel<<<NPAIR, 256, 0, stream>>>(x, meta, Aall);
    repack_kernel<<<(int)(W13_DWORDS/1024), 256, 0, stream>>>(w13p, W13d, (int)(W13_DWORDS/4));
    gemm1_kernel<<<dim3(IDIM/64, NPAIR/128, NE), 256, 0, stream>>>(Aall, W13d, w13s, w13z, meta, h);
    repack_kernel<<<(int)(W2_DWORDS/1024), 256, 0, stream>>>(w2p, W2d, (int)(W2_DWORDS/4));
    gemm2_kernel<<<dim3(DDIM/128, NPAIR/128, NE), 256, 0, stream>>>(h, W2d, w2s, w2z, tw, meta, yp);
    combine_kernel<<<(T_TOK*DDIM/4)/256, 256, 0, stream>>>(yp, out);
}